// Round 5
// baseline (37.202 us; speedup 1.0000x reference)
//
#include <hip/hip_runtime.h>
#include <math.h>

constexpr int NB    = 128;
constexpr int NPAIR = NB * (NB - 1) / 2;        // 8128
constexpr int NANG  = NB - 2;                   // 126
constexpr int NDIH  = NB - 3;                   // 125
constexpr int ROW   = NPAIR + NANG + 2 * NDIH;  // 8504

// ---------------- Kernel 1: pairwise distances (HBM-store-bound) -------------
// Lean on purpose: __launch_bounds__(128,8) pins VGPR<=64 -> 8 waves/SIMD.
__global__ __launch_bounds__(128, 8) void dist_kernel(
        const float* __restrict__ data, float* __restrict__ out) {
    __shared__ float4 s4[NB];                    // (x,y,z,0) per bead
    const int b = blockIdx.x;
    const int t = threadIdx.x;                   // 0..127 == bead index
    const float* src = data + (size_t)b * (NB * 3);

    s4[t] = make_float4(src[3 * t], src[3 * t + 1], src[3 * t + 2], 0.0f);
    __syncthreads();

    float* orow = out + (size_t)b * ROW;

    // Register band: lane t holds beads t, t-1, t-2, t-3.
    float px[4], py[4], pz[4];
    #pragma unroll
    for (int k = 0; k < 4; ++k) {
        int idx = t - k; if (idx < 0) idx = 0;   // clamped; masked at store
        float4 v = s4[idx];
        px[k] = v.x; py[k] = v.y; pz[k] = v.z;
    }

    // 4 rows per ds_read_b128: pj=s4[t+off] pairs with band -> rows off..off+3,
    // store position i=t-k (stride-1 across lanes, coalesced).
    int base = 0;                                // row-base B(off), B(1)=0
    #pragma unroll 2
    for (int off = 1; off < NB; off += 4) {
        const int len = NB - off;                // row `off` length
        int bk0 = base;
        int bk1 = bk0 + len;
        int bk2 = bk1 + len - 1;
        int bk3 = bk2 + len - 2;
        base    = bk3 + len - 3;                 // B(off+4)
        if (t < len) {                           // wave 1 execz-skips off>63
            float4 pj = s4[t + off];
            float dx, dy, dz, d;
            dx = pj.x - px[0]; dy = pj.y - py[0]; dz = pj.z - pz[0];
            d = __builtin_amdgcn_sqrtf(dx*dx + dy*dy + dz*dz);
            orow[bk0 + t] = d;
            dx = pj.x - px[1]; dy = pj.y - py[1]; dz = pj.z - pz[1];
            d = __builtin_amdgcn_sqrtf(dx*dx + dy*dy + dz*dz);
            if (t >= 1) orow[bk1 + t - 1] = d;
            dx = pj.x - px[2]; dy = pj.y - py[2]; dz = pj.z - pz[2];
            d = __builtin_amdgcn_sqrtf(dx*dx + dy*dy + dz*dz);
            if (t >= 2) orow[bk2 + t - 2] = d;
            dx = pj.x - px[3]; dy = pj.y - py[3]; dz = pj.z - pz[3];
            d = __builtin_amdgcn_sqrtf(dx*dx + dy*dy + dz*dz);
            if (t >= 3) orow[bk3 + t - 3] = d;
        }
    }
}

// ---------------- Kernel 2: angles + dihedrals (tiny, VALU-heavy) ------------
__global__ __launch_bounds__(128) void angle_kernel(
        const float* __restrict__ data, float* __restrict__ out) {
    __shared__ float4 s4[NB];
    const int b = blockIdx.x;
    const int t = threadIdx.x;
    const float* src = data + (size_t)b * (NB * 3);

    s4[t] = make_float4(src[3 * t], src[3 * t + 1], src[3 * t + 2], 0.0f);
    __syncthreads();

    float* orow = out + (size_t)b * ROW;

    for (int v = t; v < NANG + 2 * NDIH; v += 128) {
        if (v < NANG) {
            int k = v;
            float4 p0 = s4[k], p1 = s4[k + 1], p2 = s4[k + 2];
            float a0x = p1.x - p0.x, a0y = p1.y - p0.y, a0z = p1.z - p0.z;
            float a1x = p2.x - p1.x, a1y = p2.y - p1.y, a1z = p2.z - p1.z;
            float d  = a0x * a1x + a0y * a1y + a0z * a1z;
            float r0 = rsqrtf(a0x * a0x + a0y * a0y + a0z * a0z);
            float r1 = rsqrtf(a1x * a1x + a1y * a1y + a1z * a1z);
            float c  = d * r0 * r1;
            c = fminf(1.0f, fmaxf(-1.0f, c));
            orow[NPAIR + k] = acosf(c);
        } else {
            int k = (v < NANG + NDIH) ? (v - NANG) : (v - NANG - NDIH);
            float4 p0 = s4[k], p1 = s4[k + 1], p2 = s4[k + 2], p3 = s4[k + 3];
            float e0x = p1.x - p0.x, e0y = p1.y - p0.y, e0z = p1.z - p0.z;
            float e1x = p2.x - p1.x, e1y = p2.y - p1.y, e1z = p2.z - p1.z;
            float e2x = p3.x - p2.x, e2y = p3.y - p2.y, e2z = p3.z - p2.z;
            // c0 = e0 x e1 ; c1 = e1 x e2
            float c0x = e0y * e1z - e0z * e1y;
            float c0y = e0z * e1x - e0x * e1z;
            float c0z = e0x * e1y - e0y * e1x;
            float c1x = e1y * e2z - e1z * e2y;
            float c1y = e1z * e2x - e1x * e2z;
            float c1z = e1x * e2y - e1y * e2x;
            float rn0 = rsqrtf(c0x * c0x + c0y * c0y + c0z * c0z);
            if (v < NANG + NDIH) {
                float d   = c0x * c1x + c0y * c1y + c0z * c1z;
                float rn1 = rsqrtf(c1x * c1x + c1y * c1y + c1z * c1z);
                orow[NPAIR + NANG + k] = d * rn0 * rn1;
            } else {
                // plane = c1 x e1
                float qx = c1y * e1z - c1z * e1y;
                float qy = c1z * e1x - c1x * e1z;
                float qz = c1x * e1y - c1y * e1x;
                float d  = c0x * qx + c0y * qy + c0z * qz;
                float rp = rsqrtf(qx * qx + qy * qy + qz * qz);
                orow[NPAIR + NANG + NDIH + k] = d * rn0 * rp;
            }
        }
    }
}

extern "C" void kernel_launch(void* const* d_in, const int* in_sizes, int n_in,
                              void* d_out, int out_size, void* d_ws, size_t ws_size,
                              hipStream_t stream) {
    const float* data = (const float*)d_in[0];
    float* out = (float*)d_out;
    const int batch = in_sizes[0] / (NB * 3);   // 4096
    dist_kernel<<<batch, 128, 0, stream>>>(data, out);
    angle_kernel<<<batch, 128, 0, stream>>>(data, out);
}